// Round 10
// baseline (112.462 us; speedup 1.0000x reference)
//
#include <hip/hip_runtime.h>
#include <stdint.h>

// triplet_loss_cl: loss = mean_i(-log(softmax(q G^T)[i,i] + 1e-5)), N=8192, D=256.
// Flash-style, never materialize logits. q pre-scaled by log2(e); MFMA C-input
// initialized to -KOFF so logits exit MFMA already offset; epilogue is bare exp2.
// Offset cancels exactly in p = exp2(l_ii)/sum exp2(l).
//
// Round 10: r9's spill-proof footprint (32 rows/wave fp8, afrag[2][8]=32 regs)
// with LDS and ALL barriers deleted: B fragments are direct coalesced b64 loads
// from the 2 MB L2-resident gb (cs = blockIdx&31 -> cs mod 8 pins an XCD's hot
// B-set to 256 KB). No DMA, no syncthreads -> no vmcnt(0) barrier drains; the
// compiler hoists B loads across cf-groups with fine-grained vmcnt. ~100 VGPR,
// 4 waves/SIMD. r3 tried this shape but was register-poisoned (128-reg bf16
// afrag + 64 live acc); at 32+8 it is clean.

#define LOG2E 1.44269504f
#define KOFF  92.3324826f          // 64 * log2(e); cancels exactly in p = e_ii/Z

typedef __attribute__((ext_vector_type(4))) float f32x4;
typedef long long i64;

// ---- kernel 0: fp32 row-major [8192][256] -> fp8 e4m3 panel-fragment layout ----
// Panel = 64 rows (16 KB). Chunk s = ks*4+cf (512 B) holds rows cf*16+l15,
// k = ks*32 + quad*8 .. +8, at byte (quad*16+l15)*8. q pre-scaled by log2(e).
__global__ __launch_bounds__(256) void k_cvt(const float* __restrict__ q,
                                             const float* __restrict__ g,
                                             char* __restrict__ qb,
                                             char* __restrict__ gb) {
    int o = blockIdx.x * 256 + threadIdx.x;        // grid 2048: q then g
    const float* src = q;
    char* dst = qb;
    float sc = LOG2E;
    if (o >= 262144) { o -= 262144; src = g; dst = gb; sc = 1.0f; }
    int row = o >> 5, slot = o & 31;
    int ks = slot >> 2, quad = slot & 3;
    const float4* sp = (const float4*)(src + row * 256 + slot * 8);
    float4 a = sp[0], b = sp[1];
    uint32_t w0 = __builtin_amdgcn_cvt_pk_fp8_f32(a.x * sc, a.y * sc, 0, false);
    w0 = __builtin_amdgcn_cvt_pk_fp8_f32(a.z * sc, a.w * sc, w0, true);
    uint32_t w1 = __builtin_amdgcn_cvt_pk_fp8_f32(b.x * sc, b.y * sc, 0, false);
    w1 = __builtin_amdgcn_cvt_pk_fp8_f32(b.z * sc, b.w * sc, w1, true);
    int p = row >> 6, cf = (row >> 4) & 3, l15 = row & 15;
    uint2 wv; wv.x = w0; wv.y = w1;
    *(uint2*)(dst + (size_t)p * 16384 + (ks * 4 + cf) * 512 + (quad * 16 + l15) * 8) = wv;
}

// ---- kernel 1: per-row Z partials (+ diagonal offset-logits), LDS/barrier-free ----
// grid 2048 = 64 row-tiles (BM=128) x 32 col-splits (256 cols). 4 waves x 32 rows.
__global__ __launch_bounds__(256, 2) void k_main(const char* __restrict__ qb,
                                                 const char* __restrict__ gb,
                                                 float* __restrict__ zpart,
                                                 float* __restrict__ diag) {
    const int tid  = threadIdx.x;
    const int wave = tid >> 6;
    const int lane = tid & 63;
    const int l15  = lane & 15;
    const int quad = lane >> 4;
    const int t    = blockIdx.x >> 5;              // row-tile (128 rows)
    const int cs   = blockIdx.x & 31;              // col-split (256 cols)
    const int rowbase = t * 128 + wave * 32;
    const char* gp0 = gb + (size_t)(cs * 4) * 16384 + lane * 8;

    // A fragments: panel t*2+(wave>>1), rows (wave&1)*32 + rg*16 + l15.
    i64 afrag[2][8];                               // 32 VGPRs
    {
        const char* qp = qb + (size_t)(t * 2 + (wave >> 1)) * 16384 + lane * 8;
        const int cfa = (wave & 1) * 2;
#pragma unroll
        for (int rg = 0; rg < 2; ++rg)
#pragma unroll
            for (int ks = 0; ks < 8; ++ks)
                afrag[rg][ks] = *(const i64*)(qp + ((ks * 4 + cfa + rg) << 9));
    }

    float zacc[2][4];
#pragma unroll
    for (int rg = 0; rg < 2; ++rg)
#pragma unroll
        for (int r = 0; r < 4; ++r) zacc[rg][r] = 0.f;

    const bool bd  = (cs == (t >> 1));             // block's col-slice hits diagonal
    const int  jtd = (t & 1) * 2 + (wave >> 1);    // jt tile holding our diag rows

#pragma unroll
    for (int jt = 0; jt < 4; ++jt) {
        const char* gp = gp0 + (jt << 14);
        const bool dgt = bd && (jt == jtd);        // this tile holds our diagonal
#pragma unroll
        for (int cf = 0; cf < 4; ++cf) {
            f32x4 acc[2];
            acc[0] = (f32x4){-KOFF, -KOFF, -KOFF, -KOFF};
            acc[1] = acc[0];
#pragma unroll
            for (int ks = 0; ks < 8; ++ks) {
                i64 b = *(const i64*)(gp + ((ks * 4 + cf) << 9));
                acc[0] = __builtin_amdgcn_mfma_f32_16x16x32_fp8_fp8(
                    afrag[0][ks], b, acc[0], 0, 0, 0);
                acc[1] = __builtin_amdgcn_mfma_f32_16x16x32_fp8_fp8(
                    afrag[1][ks], b, acc[1], 0, 0, 0);
            }
            // C/D layout: col=lane&15, row=quad*4+reg (dtype-independent, m121+)
#pragma unroll
            for (int rg = 0; rg < 2; ++rg)
#pragma unroll
                for (int r = 0; r < 4; ++r)
                    zacc[rg][r] += __builtin_amdgcn_exp2f(acc[rg][r]);
            if (dgt) {                             // diag at cf == (wave&1)*2 + rg
#pragma unroll
                for (int rg = 0; rg < 2; ++rg)
                    if (cf == (wave & 1) * 2 + rg) {
#pragma unroll
                        for (int r = 0; r < 4; ++r)
                            if (quad * 4 + r == l15)
                                diag[rowbase + rg * 16 + l15] = acc[rg][r];
                    }
            }
        }
    }

    // fold the 16 column-lane-classes (lanes differing in bits 0..3 share a row)
#pragma unroll
    for (int d = 1; d < 16; d <<= 1)
#pragma unroll
        for (int rg = 0; rg < 2; ++rg)
#pragma unroll
            for (int r = 0; r < 4; ++r)
                zacc[rg][r] += __shfl_xor(zacc[rg][r], d, 64);

    if (l15 == 0) {
#pragma unroll
        for (int rg = 0; rg < 2; ++rg)
#pragma unroll
            for (int r = 0; r < 4; ++r)
                zpart[(rowbase + rg * 16 + quad * 4 + r) * 32 + cs] = zacc[rg][r];
    }
}

// ---- kernel 2a: per-row loss, 32-block tree ----
__global__ __launch_bounds__(256) void k_fin1(const float* __restrict__ zpart,
                                              const float* __restrict__ diag,
                                              float* __restrict__ partial) {
    __shared__ float red[4];
    int r = blockIdx.x * 256 + threadIdx.x;
    const float4* z = (const float4*)(zpart + r * 32);
    float Z = 0.f;
#pragma unroll
    for (int i = 0; i < 8; ++i) {
        float4 a = z[i];
        Z += (a.x + a.y) + (a.z + a.w);
    }
    float p = __builtin_amdgcn_exp2f(diag[r]) / Z;  // diag already has -KOFF folded
    float v = -logf(p + 1e-5f);
#pragma unroll
    for (int dd = 1; dd < 64; dd <<= 1) v += __shfl_xor(v, dd, 64);
    if ((threadIdx.x & 63) == 0) red[threadIdx.x >> 6] = v;
    __syncthreads();
    if (threadIdx.x == 0)
        partial[blockIdx.x] = (red[0] + red[1]) + (red[2] + red[3]);
}

// ---- kernel 2b: final reduce ----
__global__ void k_fin2(const float* __restrict__ partial, float* __restrict__ out) {
    float v = (threadIdx.x < 32) ? partial[threadIdx.x] : 0.f;
#pragma unroll
    for (int d = 1; d < 32; d <<= 1) v += __shfl_xor(v, d, 64);
    if (threadIdx.x == 0) out[0] = v * (1.f / 8192.f);
}

extern "C" void kernel_launch(void* const* d_in, const int* in_sizes, int n_in,
                              void* d_out, int out_size, void* d_ws, size_t ws_size,
                              hipStream_t stream) {
    const float* q = (const float*)d_in[0];
    const float* g = (const float*)d_in[1];
    char* ws = (char*)d_ws;
    char*  qb     = ws;                                        // 2 MiB fp8 panels
    char*  gb     = ws + (2u << 20);                           // 2 MiB fp8 panels
    float* diag   = (float*)(ws + (4u << 20));                 // 32 KiB
    float* zpart  = (float*)(ws + (4u << 20) + (32u << 10));   // 1 MiB
    float* partial= (float*)(ws + (4u << 20) + (1056u << 10)); // 128 B
    k_cvt <<<2048, 256, 0, stream>>>(q, g, qb, gb);
    k_main<<<2048, 256, 0, stream>>>(qb, gb, zpart, diag);
    k_fin1<<<32,   256, 0, stream>>>(zpart, diag, partial);
    k_fin2<<<1,     64, 0, stream>>>(partial, (float*)d_out);
    (void)in_sizes; (void)n_in; (void)out_size; (void)ws_size;
}

// Round 11
// 102.739 us; speedup vs baseline: 1.0946x; 1.0946x over previous
//
#include <hip/hip_runtime.h>
#include <stdint.h>

// triplet_loss_cl: loss = mean_i(-log(softmax(q G^T)[i,i] + 1e-5)), N=8192, D=256.
// Flash-style, never materialize logits. q pre-scaled by log2(e); MFMA C-input
// initialized to -KOFF so logits exit MFMA already offset; epilogue is bare exp2.
// Offset cancels exactly in p = exp2(l_ii)/sum exp2(l).
//
// Round 11: r9 base (32 rows/wave fp8, LDS DMA staging, 92 VGPR clean) +
// per-wave ILP fixes: (a) register prefetch of next cf-group's 8 ds_read_b64
// (bb[2][8]) so LDS latency hides behind the previous group's MFMAs;
// (b) 4 independent acc chains (ks-split 0-3 / 4-7, summed pre-exp2) halving
// chain depth. ~110 VGPR -> 4 waves/SIMD, no spill. r10 showed direct-L2 B
// (no LDS) is WORSE (55 vs ~45 us: exposed 200-cyc L2 latency).

#define LOG2E 1.44269504f
#define KOFF  92.3324826f          // 64 * log2(e); cancels exactly in p = e_ii/Z

typedef __attribute__((ext_vector_type(4))) float f32x4;
typedef long long i64;

typedef __attribute__((address_space(1))) const uint32_t gu32;
typedef __attribute__((address_space(3))) uint32_t lu32;

// ---- kernel 0: fp32 row-major [8192][256] -> fp8 e4m3 panel-fragment layout ----
// Panel = 64 rows (16 KB). Chunk s = ks*4+cf (512 B) holds rows cf*16+l15,
// k = ks*32 + quad*8 .. +8, at byte (quad*16+l15)*8. q pre-scaled by log2(e).
__global__ __launch_bounds__(256) void k_cvt(const float* __restrict__ q,
                                             const float* __restrict__ g,
                                             char* __restrict__ qb,
                                             char* __restrict__ gb) {
    int o = blockIdx.x * 256 + threadIdx.x;        // grid 2048: q then g
    const float* src = q;
    char* dst = qb;
    float sc = LOG2E;
    if (o >= 262144) { o -= 262144; src = g; dst = gb; sc = 1.0f; }
    int row = o >> 5, slot = o & 31;
    int ks = slot >> 2, quad = slot & 3;
    const float4* sp = (const float4*)(src + row * 256 + slot * 8);
    float4 a = sp[0], b = sp[1];
    uint32_t w0 = __builtin_amdgcn_cvt_pk_fp8_f32(a.x * sc, a.y * sc, 0, false);
    w0 = __builtin_amdgcn_cvt_pk_fp8_f32(a.z * sc, a.w * sc, w0, true);
    uint32_t w1 = __builtin_amdgcn_cvt_pk_fp8_f32(b.x * sc, b.y * sc, 0, false);
    w1 = __builtin_amdgcn_cvt_pk_fp8_f32(b.z * sc, b.w * sc, w1, true);
    int p = row >> 6, cf = (row >> 4) & 3, l15 = row & 15;
    uint2 wv; wv.x = w0; wv.y = w1;
    *(uint2*)(dst + (size_t)p * 16384 + (ks * 4 + cf) * 512 + (quad * 16 + l15) * 8) = wv;
}

// ---- kernel 1: per-row Z partials (+ diagonal offset-logits) ----
// grid 2048 = 64 row-tiles (BM=128) x 32 col-splits (256 cols). 4 waves x 32 rows.
// Per jt: DMA 16 KB, sync, [prefetch cf+1 B-regs | 16 MFMA on cf | exp2], sync.
__global__ __launch_bounds__(256, 2) void k_main(const char* __restrict__ qb,
                                                 const char* __restrict__ gb,
                                                 float* __restrict__ zpart,
                                                 float* __restrict__ diag) {
    __shared__ char lds[16384];                    // one 64-col fp8 B tile
    const int tid  = threadIdx.x;
    const int wave = tid >> 6;
    const int lane = tid & 63;
    const int l15  = lane & 15;
    const int quad = lane >> 4;
    const int t    = blockIdx.x >> 5;              // row-tile (128 rows)
    const int cs   = blockIdx.x & 31;              // col-split (256 cols)
    const int rowbase = t * 128 + wave * 32;
    const char* gp0 = gb + (size_t)(cs * 4) * 16384;

    // A fragments: panel t*2+(wave>>1), rows (wave&1)*32 + rg*16 + l15.
    i64 afrag[2][8];                               // 32 VGPRs
    {
        const char* qp = qb + (size_t)(t * 2 + (wave >> 1)) * 16384 + lane * 8;
        const int cfa = (wave & 1) * 2;
#pragma unroll
        for (int rg = 0; rg < 2; ++rg)
#pragma unroll
            for (int ks = 0; ks < 8; ++ks)
                afrag[rg][ks] = *(const i64*)(qp + ((ks * 4 + cfa + rg) << 9));
    }

    float zacc[2][4];
#pragma unroll
    for (int rg = 0; rg < 2; ++rg)
#pragma unroll
        for (int r = 0; r < 4; ++r) zacc[rg][r] = 0.f;

    const bool bd  = (cs == (t >> 1));             // block's col-slice hits diagonal
    const int  jtd = (t & 1) * 2 + (wave >> 1);    // jt tile holding our diag rows

    for (int jt = 0; jt < 4; ++jt) {
        const char* gp = gp0 + (jt << 14);
        // stage 16 KB: 4 waves x 4 x 1KB DMA (linear; dest = uniform + lane*16)
#pragma unroll
        for (int i = 0; i < 4; ++i) {
            int c = wave * 4 + i;
            __builtin_amdgcn_global_load_lds(
                (gu32*)(gp + (c << 10) + (lane << 4)),
                (lu32*)(lds + (c << 10)), 16, 0, 0);
        }
        __syncthreads();

        const bool dgt = bd && (jt == jtd);        // this tile holds our diagonal

        i64 bb[2][8];                              // cur/next B double buffer, 32 regs
#pragma unroll
        for (int ks = 0; ks < 8; ++ks)             // preload cf=0
            bb[0][ks] = *(const i64*)(lds + ((ks * 4) << 9) + lane * 8);

#pragma unroll
        for (int cf = 0; cf < 4; ++cf) {
            const i64* cur = bb[cf & 1];
            i64*       nxt = bb[(cf + 1) & 1];
            if (cf < 3) {                          // prefetch next group's B from LDS
#pragma unroll
                for (int ks = 0; ks < 8; ++ks)
                    nxt[ks] = *(const i64*)(lds + ((ks * 4 + cf + 1) << 9) + lane * 8);
            }
            // 4 independent MFMA chains: (rg 0/1) x (ks-half a/b), depth 4 each
            f32x4 a0 = (f32x4){-KOFF, -KOFF, -KOFF, -KOFF};
            f32x4 a1 = a0;
            f32x4 b0 = (f32x4){0.f, 0.f, 0.f, 0.f};
            f32x4 b1 = b0;
#pragma unroll
            for (int ks = 0; ks < 4; ++ks) {
                a0 = __builtin_amdgcn_mfma_f32_16x16x32_fp8_fp8(afrag[0][ks], cur[ks], a0, 0, 0, 0);
                a1 = __builtin_amdgcn_mfma_f32_16x16x32_fp8_fp8(afrag[1][ks], cur[ks], a1, 0, 0, 0);
                b0 = __builtin_amdgcn_mfma_f32_16x16x32_fp8_fp8(afrag[0][ks + 4], cur[ks + 4], b0, 0, 0, 0);
                b1 = __builtin_amdgcn_mfma_f32_16x16x32_fp8_fp8(afrag[1][ks + 4], cur[ks + 4], b1, 0, 0, 0);
            }
            f32x4 s0 = a0 + b0;
            f32x4 s1 = a1 + b1;
            // C/D layout: col=lane&15, row=quad*4+reg (dtype-independent, m121+)
#pragma unroll
            for (int r = 0; r < 4; ++r) {
                zacc[0][r] += __builtin_amdgcn_exp2f(s0[r]);
                zacc[1][r] += __builtin_amdgcn_exp2f(s1[r]);
            }
            if (dgt) {                             // diag at cf == (wave&1)*2 + rg
                if (cf == (wave & 1) * 2) {
#pragma unroll
                    for (int r = 0; r < 4; ++r)
                        if (quad * 4 + r == l15)
                            diag[rowbase + l15] = s0[r];
                }
                if (cf == (wave & 1) * 2 + 1) {
#pragma unroll
                    for (int r = 0; r < 4; ++r)
                        if (quad * 4 + r == l15)
                            diag[rowbase + 16 + l15] = s1[r];
                }
            }
        }
        __syncthreads();
    }

    // fold the 16 column-lane-classes (lanes differing in bits 0..3 share a row)
#pragma unroll
    for (int d = 1; d < 16; d <<= 1)
#pragma unroll
        for (int rg = 0; rg < 2; ++rg)
#pragma unroll
            for (int r = 0; r < 4; ++r)
                zacc[rg][r] += __shfl_xor(zacc[rg][r], d, 64);

    if (l15 == 0) {
#pragma unroll
        for (int rg = 0; rg < 2; ++rg)
#pragma unroll
            for (int r = 0; r < 4; ++r)
                zpart[(rowbase + rg * 16 + quad * 4 + r) * 32 + cs] = zacc[rg][r];
    }
}

// ---- kernel 2a: per-row loss, 32-block tree ----
__global__ __launch_bounds__(256) void k_fin1(const float* __restrict__ zpart,
                                              const float* __restrict__ diag,
                                              float* __restrict__ partial) {
    __shared__ float red[4];
    int r = blockIdx.x * 256 + threadIdx.x;
    const float4* z = (const float4*)(zpart + r * 32);
    float Z = 0.f;
#pragma unroll
    for (int i = 0; i < 8; ++i) {
        float4 a = z[i];
        Z += (a.x + a.y) + (a.z + a.w);
    }
    float p = __builtin_amdgcn_exp2f(diag[r]) / Z;  // diag already has -KOFF folded
    float v = -logf(p + 1e-5f);
#pragma unroll
    for (int dd = 1; dd < 64; dd <<= 1) v += __shfl_xor(v, dd, 64);
    if ((threadIdx.x & 63) == 0) red[threadIdx.x >> 6] = v;
    __syncthreads();
    if (threadIdx.x == 0)
        partial[blockIdx.x] = (red[0] + red[1]) + (red[2] + red[3]);
}

// ---- kernel 2b: final reduce ----
__global__ void k_fin2(const float* __restrict__ partial, float* __restrict__ out) {
    float v = (threadIdx.x < 32) ? partial[threadIdx.x] : 0.f;
#pragma unroll
    for (int d = 1; d < 32; d <<= 1) v += __shfl_xor(v, d, 64);
    if (threadIdx.x == 0) out[0] = v * (1.f / 8192.f);
}

extern "C" void kernel_launch(void* const* d_in, const int* in_sizes, int n_in,
                              void* d_out, int out_size, void* d_ws, size_t ws_size,
                              hipStream_t stream) {
    const float* q = (const float*)d_in[0];
    const float* g = (const float*)d_in[1];
    char* ws = (char*)d_ws;
    char*  qb     = ws;                                        // 2 MiB fp8 panels
    char*  gb     = ws + (2u << 20);                           // 2 MiB fp8 panels
    float* diag   = (float*)(ws + (4u << 20));                 // 32 KiB
    float* zpart  = (float*)(ws + (4u << 20) + (32u << 10));   // 1 MiB
    float* partial= (float*)(ws + (4u << 20) + (1056u << 10)); // 128 B
    k_cvt <<<2048, 256, 0, stream>>>(q, g, qb, gb);
    k_main<<<2048, 256, 0, stream>>>(qb, gb, zpart, diag);
    k_fin1<<<32,   256, 0, stream>>>(zpart, diag, partial);
    k_fin2<<<1,     64, 0, stream>>>(partial, (float*)d_out);
    (void)in_sizes; (void)n_in; (void)out_size; (void)ws_size;
}